// Round 1
// baseline (1636.978 us; speedup 1.0000x reference)
//
#include <hip/hip_runtime.h>

#define N_NODES 50000
#define N_EDGES 400000

typedef __bf16 bf16x8 __attribute__((ext_vector_type(8)));
typedef float f32x4 __attribute__((ext_vector_type(4)));

__device__ __forceinline__ float bflo(uint u){ union{uint i; float f;} v; v.i = u<<16; return v.f; }
__device__ __forceinline__ float bfhi(uint u){ union{uint i; float f;} v; v.i = u & 0xffff0000u; return v.f; }
__device__ __forceinline__ float bf2f(ushort u){ union{uint i; float f;} v; v.i = ((uint)u)<<16; return v.f; }
__device__ __forceinline__ ushort f2bf(float f){
  union{float f; uint i;} v; v.f = f;
  uint r = (v.i + 0x7fffu + ((v.i>>16)&1u))>>16;
  return (ushort)r;
}
__device__ __forceinline__ uint pack2(float a, float b){
  return (uint)f2bf(a) | ((uint)f2bf(b)<<16);
}

// ---------------- f32 -> bf16 convert ------------------------------------------
__global__ __launch_bounds__(256) void f32_to_bf16(
    const float* __restrict__ in, ushort* __restrict__ out, int n)
{
  int i = blockIdx.x*256 + threadIdx.x;
  if (i < n) out[i] = f2bf(in[i]);
}

// ---------------- LayerNorm: one wave per node, 2 channels/lane ----------------
__global__ __launch_bounds__(256) void ln_kernel(
    const float* __restrict__ x, const float* __restrict__ w,
    const float* __restrict__ b, ushort* __restrict__ xn)
{
  int n = blockIdx.x*4 + (threadIdx.x>>6);
  if (n >= N_NODES) return;
  int lane = threadIdx.x & 63;
  float2 xp = ((const float2*)x)[(size_t)n*64 + lane];
  float x0 = xp.x, x1 = xp.y;
  float s = x0 + x1, s2 = x0*x0 + x1*x1;
  #pragma unroll
  for (int off=1; off<64; off<<=1){ s += __shfl_xor(s,off); s2 += __shfl_xor(s2,off); }
  float mu  = s*(1.0f/128.0f);
  float var = s2*(1.0f/128.0f) - mu*mu;
  float inv = 1.0f/sqrtf(var + 1e-5f);
  float2 wp = ((const float2*)w)[lane];
  float2 bp = ((const float2*)b)[lane];
  float y0 = (x0-mu)*inv*wp.x + bp.x;
  float y1 = (x1-mu)*inv*wp.y + bp.y;
  ((uint*)xn)[(size_t)n*64 + lane] = pack2(y0, y1);
}

// ---------------- Counting sort by dst -----------------------------------------
__global__ __launch_bounds__(256) void hist_kernel(
    const int* __restrict__ ei, int* __restrict__ cnt)
{
  int e = blockIdx.x*256 + threadIdx.x;
  if (e < N_EDGES) atomicAdd(&cnt[ei[N_EDGES + e]], 1);
}

// single-block exclusive scan of cnt[N_NODES] -> offs[N_NODES+1], cursor copy
__global__ __launch_bounds__(1024) void scan_kernel(
    const int* __restrict__ cnt, int* __restrict__ offs, int* __restrict__ cursor)
{
  __shared__ int wsum[16];
  __shared__ int carry_s;
  int tid = threadIdx.x, lane = tid & 63, wid = tid >> 6;
  if (tid == 0) carry_s = 0;
  __syncthreads();
  for (int base = 0; base < N_NODES; base += 1024){
    int i = base + tid;
    int v = (i < N_NODES) ? cnt[i] : 0;
    int x = v;
    #pragma unroll
    for (int o=1;o<64;o<<=1){ int t=__shfl_up(x,o); if (lane>=o) x+=t; }
    if (lane == 63) wsum[wid] = x;
    __syncthreads();
    if (wid == 0){
      int ws = (lane < 16) ? wsum[lane] : 0;
      #pragma unroll
      for (int o=1;o<16;o<<=1){ int t=__shfl_up(ws,o); if (lane>=o) ws+=t; }
      if (lane < 16) wsum[lane] = ws;
    }
    __syncthreads();
    int wpre = (wid > 0) ? wsum[wid-1] : 0;
    int exc = x + wpre - v;
    int total = wsum[15];
    int o_ = carry_s + exc;
    if (i < N_NODES){ offs[i] = o_; cursor[i] = o_; }
    __syncthreads();
    if (tid == 0) carry_s += total;
    __syncthreads();
  }
  if (tid == 0) offs[N_NODES] = carry_s;
}

__global__ __launch_bounds__(256) void scatter_kernel(
    const int* __restrict__ ei, int* __restrict__ cursor,
    int* __restrict__ perm, int* __restrict__ srcs)
{
  int e = blockIdx.x*256 + threadIdx.x;
  if (e >= N_EDGES) return;
  int d = ei[N_EDGES + e];
  int pos = atomicAdd(&cursor[d], 1);
  perm[pos] = e;
  srcs[pos] = ei[e];
}

// ---------------- Generic MFMA GEMM: act(A[M,K] @ W[Nc,K]^T + bias) ------------
// 128x128 tile, BK=32, 4 waves, each wave 64x64 (4x4 frags of 16x16x32 bf16).
// AF32: A operand is f32 in global, converted to bf16 during LDS staging.
// ridx (AF32 only): A row gather — A row r reads Af[ridx[r]*K ...].
// Epilogue MODEs:
//  0: bf16 store          1: silu -> bf16 store
//  4: aux2f[row*Nc+c] *= vv
//  5: Cf[row*Nc+c] = aux1f[row*Nc+c] + vv    (dx = vdot + o3)
//  6: Cf[row*Nc+c] = vv*bf16(aux1)[(row/3)*Nc+c] + aux2f[row*Nc+c]  (dvec)
//  7: dual-B: atomicAdd(aux2f[(row/3)*Nc+c], (acc1+b1)*(acc2+b2))   (vec_dot)
#define LDP 40  // padded LDS row (bf16 elems)

template<int MODE, int AF32>
__global__ __launch_bounds__(256) void gemm_bt(
    const void* __restrict__ Av, const ushort* __restrict__ W,
    const ushort* __restrict__ W2,
    const float* __restrict__ bias, const float* __restrict__ bias2,
    void* Cptr, const void* aux1, void* aux2,
    int M, int K, int Nc, const int* __restrict__ ridx)
{
  __shared__ ushort As[128*LDP];
  __shared__ ushort Bs[128*LDP];
  __shared__ ushort Bs2[(MODE==7) ? 128*LDP : 2];
  const int tid = threadIdx.x;
  const int row0 = blockIdx.x*128, col0 = blockIdx.y*128;
  const int wave = tid>>6, lane = tid&63;
  const int wm = (wave>>1)*64, wn = (wave&1)*64;
  const int lr = lane&15, lq = lane>>4;
  f32x4 acc[4][4] = {};
  f32x4 acc2[4][4] = {};   // only used when MODE==7

  for (int k0=0; k0<K; k0+=32){
    #pragma unroll
    for (int rnd=0; rnd<2; rnd++){
      int e4 = (rnd*256 + tid)*8;
      int r = e4>>5, c = e4&31;
      int gk = k0 + c;
      { // A tile
        int gr = row0 + r;
        uint2 lo, hi;
        if (AF32){
          const float* Af = (const float*)Av;
          int ga = gr;
          if (ridx && gr < M) ga = ridx[gr];
          if (gr < M && gk + 8 <= K){
            const float* p = Af + (size_t)ga*K + gk;
            float4 f0 = *(const float4*)p;
            float4 f1 = *(const float4*)(p+4);
            lo = make_uint2(pack2(f0.x,f0.y), pack2(f0.z,f0.w));
            hi = make_uint2(pack2(f1.x,f1.y), pack2(f1.z,f1.w));
          } else {
            float t[8];
            #pragma unroll
            for (int i=0;i<8;i++) t[i] = (gr<M && gk+i<K) ? Af[(size_t)ga*K + gk + i] : 0.0f;
            lo = make_uint2(pack2(t[0],t[1]), pack2(t[2],t[3]));
            hi = make_uint2(pack2(t[4],t[5]), pack2(t[6],t[7]));
          }
        } else {
          const ushort* Ab = (const ushort*)Av;
          if (gr < M && gk + 8 <= K){
            const ushort* p = Ab + (size_t)gr*K + gk;
            lo = *(const uint2*)p; hi = *(const uint2*)(p+4);
          } else {
            ushort t[8];
            #pragma unroll
            for (int i=0;i<8;i++) t[i] = (gr<M && gk+i<K) ? Ab[(size_t)gr*K + gk + i] : (ushort)0;
            lo = make_uint2(((uint)t[0])|((uint)t[1]<<16), ((uint)t[2])|((uint)t[3]<<16));
            hi = make_uint2(((uint)t[4])|((uint)t[5]<<16), ((uint)t[6])|((uint)t[7]<<16));
          }
        }
        *(uint2*)&As[r*LDP + c]     = lo;
        *(uint2*)&As[r*LDP + c + 4] = hi;
      }
      { // B tile (W rows = output channels), bf16 pre-converted
        int gr = col0 + r;
        uint2 lo, hi;
        if (gr < Nc && gk + 8 <= K){
          const ushort* p = W + (size_t)gr*K + gk;
          lo = *(const uint2*)p; hi = *(const uint2*)(p+4);
        } else {
          ushort t[8];
          #pragma unroll
          for (int i=0;i<8;i++) t[i] = (gr<Nc && gk+i<K) ? W[(size_t)gr*K + gk + i] : (ushort)0;
          lo = make_uint2(((uint)t[0])|((uint)t[1]<<16), ((uint)t[2])|((uint)t[3]<<16));
          hi = make_uint2(((uint)t[4])|((uint)t[5]<<16), ((uint)t[6])|((uint)t[7]<<16));
        }
        *(uint2*)&Bs[r*LDP + c]     = lo;
        *(uint2*)&Bs[r*LDP + c + 4] = hi;
      }
      if (MODE==7){ // second B tile
        int gr = col0 + r;
        uint2 lo, hi;
        if (gr < Nc && gk + 8 <= K){
          const ushort* p = W2 + (size_t)gr*K + gk;
          lo = *(const uint2*)p; hi = *(const uint2*)(p+4);
        } else {
          ushort t[8];
          #pragma unroll
          for (int i=0;i<8;i++) t[i] = (gr<Nc && gk+i<K) ? W2[(size_t)gr*K + gk + i] : (ushort)0;
          lo = make_uint2(((uint)t[0])|((uint)t[1]<<16), ((uint)t[2])|((uint)t[3]<<16));
          hi = make_uint2(((uint)t[4])|((uint)t[5]<<16), ((uint)t[6])|((uint)t[7]<<16));
        }
        *(uint2*)&Bs2[r*LDP + c]     = lo;
        *(uint2*)&Bs2[r*LDP + c + 4] = hi;
      }
    }
    __syncthreads();
    bf16x8 af[4], bfr[4];
    #pragma unroll
    for (int i=0;i<4;i++) af[i]  = *(const bf16x8*)&As[(wm + i*16 + lr)*LDP + lq*8];
    #pragma unroll
    for (int i=0;i<4;i++) bfr[i] = *(const bf16x8*)&Bs[(wn + i*16 + lr)*LDP + lq*8];
    #pragma unroll
    for (int i=0;i<4;i++)
      #pragma unroll
      for (int j=0;j<4;j++)
        acc[i][j] = __builtin_amdgcn_mfma_f32_16x16x32_bf16(af[i], bfr[j], acc[i][j], 0,0,0);
    if (MODE==7){
      bf16x8 bfr2[4];
      #pragma unroll
      for (int i=0;i<4;i++) bfr2[i] = *(const bf16x8*)&Bs2[(wn + i*16 + lr)*LDP + lq*8];
      #pragma unroll
      for (int i=0;i<4;i++)
        #pragma unroll
        for (int j=0;j<4;j++)
          acc2[i][j] = __builtin_amdgcn_mfma_f32_16x16x32_bf16(af[i], bfr2[j], acc2[i][j], 0,0,0);
    }
    __syncthreads();
  }

  const ushort* aux1b = (const ushort*)aux1;
  const float*  aux1f = (const float*)aux1;
  float* aux2f = (float*)aux2;

  #pragma unroll
  for (int i=0;i<4;i++){
    int rowb = row0 + wm + i*16 + lq*4;
    #pragma unroll
    for (int j=0;j<4;j++){
      int c = col0 + wn + j*16 + lr;
      float bv  = bias  ? bias[c]  : 0.0f;
      float bv2 = (MODE==7) ? bias2[c] : 0.0f;
      #pragma unroll
      for (int rg=0; rg<4; rg++){
        int row = rowb + rg;
        if (row < M){
          float vv = acc[i][j][rg] + bv;
          size_t idx = (size_t)row*Nc + c;
          if (MODE==0){
            ((ushort*)Cptr)[idx] = f2bf(vv);
          } else if (MODE==1){
            vv = vv/(1.0f + __expf(-vv));
            ((ushort*)Cptr)[idx] = f2bf(vv);
          } else if (MODE==4){
            aux2f[idx] *= vv;
          } else if (MODE==5){
            float r = aux1f[idx] + vv;
            ((float*)Cptr)[idx] = r;
          } else if (MODE==6){
            float o1 = bf2f(aux1b[(size_t)(row/3)*Nc + c]);
            float r = vv*o1 + aux2f[idx];
            ((float*)Cptr)[idx] = r;
          } else if (MODE==7){
            float vv2 = acc2[i][j][rg] + bv2;
            atomicAdd(aux2f + (size_t)(row/3)*Nc + c, vv*vv2);
          }
        }
      }
    }
  }
}

// ---------------- Aggregation: one wave per dst node, sorted edge runs ---------
// qk: combined q|k rows (node*256 ch; q = [0,128), k = [128,256))
// dkv: chunk rows of 512 ch (dk = [0,128), dv = [128,512)), sorted edge order
__global__ __launch_bounds__(256) void agg_kernel(
    int st, int len,
    const int* __restrict__ offs, const int* __restrict__ srcs,
    const int* __restrict__ perm,
    const float* __restrict__ rij, const float* __restrict__ dij,
    const ushort* __restrict__ qk, const ushort* __restrict__ v,
    const ushort* __restrict__ vecb, const ushort* __restrict__ dkv,
    float* __restrict__ x_agg, float* __restrict__ vec_agg)
{
  int n = blockIdx.x*4 + (threadIdx.x>>6);
  if (n >= N_NODES) return;
  int lane = threadIdx.x & 63;
  int s0 = offs[n], s1 = offs[n+1];
  int hi = st + len;
  int a0 = s0 > st ? s0 : st;
  int a1 = s1 < hi ? s1 : hi;
  if (a0 >= a1) return;

  const uint* qk32  = (const uint*)qk;
  const uint* v32   = (const uint*)v;
  const uint* vec32 = (const uint*)vecb;
  const uint* dkv32 = (const uint*)dkv;
  uint qp = qk32[(size_t)n*128 + lane];     // q[dst=n], hoisted per node
  int h  = lane>>3;
  int cb = h*24 + (lane&7);                 // uint idx within 48-ch head block

  float xa0=0.f, xa1=0.f;
  float vA0=0.f, vA1=0.f, vB0=0.f, vB1=0.f, vC0=0.f, vC1=0.f;

  for (int p=a0; p<a1; ++p){
    int src = srcs[p];
    int eo  = perm[p];
    uint kp = qk32[(size_t)src*128 + 64 + lane];
    const uint* dr = dkv32 + (size_t)(p-st)*256;
    uint dkp = dr[lane];
    float s = bflo(qp)*bflo(kp)*bflo(dkp) + bfhi(qp)*bfhi(kp)*bfhi(dkp);
    s += __shfl_xor(s,1); s += __shfl_xor(s,2); s += __shfl_xor(s,4);  // per-head
    float r = rij[eo];
    float cut = (r < 6.0f) ? 0.5f*(__cosf(r*0.52359877559829887f) + 1.0f) : 0.0f;
    float attn = (s/(1.0f + __expf(-s))) * cut;

    size_t vr = (size_t)src*192;
    const uint* dv = dr + 64;
    uint vx = v32[vr+cb],    dvx = dv[cb];
    uint v1 = v32[vr+cb+8],  dv1 = dv[cb+8];
    uint v2 = v32[vr+cb+16], dv2 = dv[cb+16];
    xa0 += bflo(vx)*bflo(dvx)*attn;
    xa1 += bfhi(vx)*bfhi(dvx)*attn;
    float v1m0 = bflo(v1)*bflo(dv1), v1m1 = bfhi(v1)*bfhi(dv1);
    float v2m0 = bflo(v2)*bflo(dv2), v2m1 = bfhi(v2)*bfhi(dv2);
    float d0 = dij[3*(size_t)eo], d1 = dij[3*(size_t)eo+1], d2 = dij[3*(size_t)eo+2];
    uint va  = vec32[vr + lane];
    uint vbx = vec32[vr + 64 + lane];
    uint vc  = vec32[vr + 128 + lane];
    vA0 += bflo(va)*v1m0  + v2m0*d0;  vA1 += bfhi(va)*v1m1  + v2m1*d0;
    vB0 += bflo(vbx)*v1m0 + v2m0*d1;  vB1 += bfhi(vbx)*v1m1 + v2m1*d1;
    vC0 += bflo(vc)*v1m0  + v2m0*d2;  vC1 += bfhi(vc)*v1m1  + v2m1*d2;
  }

  int f0 = 2*lane;
  float* xrow = x_agg + (size_t)n*128;
  atomicAdd(xrow+f0,   xa0);
  atomicAdd(xrow+f0+1, xa1);
  float* vrow = vec_agg + (size_t)n*384;
  atomicAdd(vrow+f0,       vA0); atomicAdd(vrow+f0+1,     vA1);
  atomicAdd(vrow+128+f0,   vB0); atomicAdd(vrow+128+f0+1, vB1);
  atomicAdd(vrow+256+f0,   vC0); atomicAdd(vrow+256+f0+1, vC1);
}

extern "C" void kernel_launch(void* const* d_in, const int* in_sizes, int n_in,
                              void* d_out, int out_size, void* d_ws, size_t ws_size,
                              hipStream_t stream)
{
  (void)in_sizes; (void)n_in; (void)out_size;
  constexpr int Nn = N_NODES, Ee = N_EDGES;
  const float* x    = (const float*)d_in[0];
  const float* vec  = (const float*)d_in[1];
  const int*   eidx = (const int*)  d_in[2];
  const float* rij  = (const float*)d_in[3];
  const float* fij  = (const float*)d_in[4];
  const float* dij  = (const float*)d_in[5];
  const float* lnw  = (const float*)d_in[6];
  const float* lnb  = (const float*)d_in[7];
  const float* Wq   = (const float*)d_in[8];
  const float* bq   = (const float*)d_in[9];
  const float* Wk   = (const float*)d_in[10];
  const float* bk   = (const float*)d_in[11];
  const float* Wv   = (const float*)d_in[12];
  const float* bv   = (const float*)d_in[13];
  const float* Wvec = (const float*)d_in[14];
  const float* bvec = (const float*)d_in[15];
  const float* Wo   = (const float*)d_in[16];
  const float* bo   = (const float*)d_in[17];
  const float* Wdk  = (const float*)d_in[18];
  const float* bdk  = (const float*)d_in[19];
  const float* Wdv  = (const float*)d_in[20];
  const float* bdv  = (const float*)d_in[21];

  // ---- d_out (f32, 25.6M floats) time-multiplexing ----
  // [0 , 6.4M)  floats: qk combined bf16 (node*256 ch) during edge phase
  //                     -> vdot(f32) -> dx(f32)
  // [6.4M,25.6M) floats: vec_agg accumulator (f32) -> dvec (f32, same addresses)
  float*  outf = (float*)d_out;
  ushort* qkb  = (ushort*)d_out;                    // 25.6 MB
  float*  vdot = outf;                              // Nn*128 f32
  float*  vagg = outf + (size_t)Nn*128;             // 3*Nn*128 f32

  // ---- workspace ----
  char* w = (char*)d_ws;
  size_t off = 0;
  auto alloc = [&](size_t bytes){ size_t o = off; off += (bytes + 255) & ~(size_t)255; return o; };

  ushort* WqkB  = (ushort*)(w + alloc(32768*2));    // Wq rows [0,128), Wk [128,256)
  ushort* WvB   = (ushort*)(w + alloc(49152*2));
  ushort* WvecB = (ushort*)(w + alloc(49152*2));
  ushort* WoB   = (ushort*)(w + alloc(49152*2));
  ushort* WdkvB = (ushort*)(w + alloc(51200*2));    // Wdk rows [0,128), Wdv [128,512)
  float*  bqk   = (float*) (w + alloc(256*4));
  float*  bdkv  = (float*) (w + alloc(512*4));
  ushort* vecb  = (ushort*)(w + alloc((size_t)3*Nn*128*2));  // 38.4 MB
  ushort* vb    = (ushort*)(w + alloc((size_t)Nn*384*2));    // 38.4 MB
  float*  xagg  = (float*) (w + alloc((size_t)Nn*128*4));    // 25.6 MB
  ushort* o1b   = (ushort*)(w + alloc((size_t)Nn*128*2));    // 12.8 MB
  int*    cnt   = (int*)   (w + alloc((size_t)Nn*4));
  int*    offs  = (int*)   (w + alloc((size_t)(Nn+1)*4));
  int*    cursor= (int*)   (w + alloc((size_t)Nn*4));
  int*    perm  = (int*)   (w + alloc((size_t)Ee*4));
  int*    srcs  = (int*)   (w + alloc((size_t)Ee*4));

  // scratch: xn (12.8 MB) -> dkv edge chunks (1024 B/edge)
  size_t sc_off = off;
  char*  sc = w + sc_off;
  ushort* xn = (ushort*)sc;
  long long chunkC = (ws_size > sc_off) ? (long long)((ws_size - sc_off) / 1024) : 64;
  if (chunkC > Ee) chunkC = Ee;
  chunkC &= ~63LL;
  if (chunkC < 64) chunkC = 64;
  ushort* dkvc = (ushort*)sc;

  // ---- weight / vec conversion ----
  f32_to_bf16<<<(16384+255)/256, 256, 0, stream>>>(Wq,   WqkB,        16384);
  f32_to_bf16<<<(16384+255)/256, 256, 0, stream>>>(Wk,   WqkB+16384,  16384);
  f32_to_bf16<<<(49152+255)/256, 256, 0, stream>>>(Wv,   WvB,   49152);
  f32_to_bf16<<<(49152+255)/256, 256, 0, stream>>>(Wvec, WvecB, 49152);
  f32_to_bf16<<<(49152+255)/256, 256, 0, stream>>>(Wo,   WoB,   49152);
  f32_to_bf16<<<(12800+255)/256, 256, 0, stream>>>(Wdk,  WdkvB,       12800);
  f32_to_bf16<<<(38400+255)/256, 256, 0, stream>>>(Wdv,  WdkvB+12800, 38400);
  f32_to_bf16<<<(3*Nn*128+255)/256, 256, 0, stream>>>(vec, vecb, 3*Nn*128);
  hipMemcpyAsync(bqk,        bq,  128*4, hipMemcpyDeviceToDevice, stream);
  hipMemcpyAsync(bqk + 128,  bk,  128*4, hipMemcpyDeviceToDevice, stream);
  hipMemcpyAsync(bdkv,       bdk, 128*4, hipMemcpyDeviceToDevice, stream);
  hipMemcpyAsync(bdkv + 128, bdv, 384*4, hipMemcpyDeviceToDevice, stream);

  hipMemsetAsync(xagg, 0, (size_t)Nn*128*4, stream);
  hipMemsetAsync(vagg, 0, (size_t)3*Nn*128*4, stream);
  hipMemsetAsync(cnt,  0, (size_t)Nn*4, stream);

  // ---- counting sort of edges by dst ----
  hist_kernel<<<(Ee+255)/256, 256, 0, stream>>>(eidx, cnt);
  scan_kernel<<<1, 1024, 0, stream>>>(cnt, offs, cursor);
  scatter_kernel<<<(Ee+255)/256, 256, 0, stream>>>(eidx, cursor, perm, srcs);

  ln_kernel<<<(Nn+3)/4, 256, 0, stream>>>(x, lnw, lnb, xn);

  // fused Q|K GEMM (Nc=256) and V GEMM
  gemm_bt<0,0><<<dim3((Nn+127)/128, 2), 256, 0, stream>>>(xn, WqkB, nullptr, bqk, nullptr, qkb, nullptr, nullptr, Nn, 128, 256, nullptr);
  gemm_bt<0,0><<<dim3((Nn+127)/128, 3), 256, 0, stream>>>(xn, WvB,  nullptr, bv,  nullptr, vb,  nullptr, nullptr, Nn, 128, 384, nullptr);

  // edge phase: fused dk|dv GEMM (Nc=512, rows gathered in sorted order),
  // then wave-per-node register aggregation. (scratch reuses xn; xn dead.)
  for (int st = 0; st < Ee; st += (int)chunkC){
    int len = Ee - st; if (len > (int)chunkC) len = (int)chunkC;
    gemm_bt<1,1><<<dim3((len+127)/128, 4), 256, 0, stream>>>(fij, WdkvB, nullptr, bdkv, nullptr, dkvc, nullptr, nullptr, len, 100, 512, perm + st);
    agg_kernel<<<(Nn+3)/4, 256, 0, stream>>>(st, len, offs, srcs, perm, rij, dij, qkb, vb, vecb, dkvc, xagg, vagg);
  }

  // qkb dead; reuse dx region as f32 vdot accumulator
  hipMemsetAsync(vdot, 0, (size_t)Nn*128*4, stream);
  gemm_bt<7,0><<<dim3((3*Nn+127)/128, 1), 256, 0, stream>>>(vecb, WvecB, WvecB + 128*128, bvec, bvec + 128, nullptr, nullptr, vdot, 3*Nn, 128, 128, nullptr);

  // o1 = xagg@Wo1^T+b ; vdot *= o2 ; dx = vdot + o3 ; dvec = vec3*o1 + vagg
  gemm_bt<0,1><<<dim3((Nn+127)/128, 1), 256, 0, stream>>>(xagg, WoB,            nullptr, bo,       nullptr, o1b,    nullptr, nullptr, Nn, 128, 128, nullptr);
  gemm_bt<4,1><<<dim3((Nn+127)/128, 1), 256, 0, stream>>>(xagg, WoB + 128*128,  nullptr, bo + 128, nullptr, nullptr, nullptr, vdot,   Nn, 128, 128, nullptr);
  gemm_bt<5,1><<<dim3((Nn+127)/128, 1), 256, 0, stream>>>(xagg, WoB + 256*128,  nullptr, bo + 256, nullptr, outf,   vdot,    nullptr, Nn, 128, 128, nullptr);
  gemm_bt<6,0><<<dim3((3*Nn+127)/128, 1), 256, 0, stream>>>(vecb, WvecB + 256*128, nullptr, bvec + 256, nullptr, outf + (size_t)Nn*128, o1b, vagg, 3*Nn, 128, 128, nullptr);
}

// Round 2
// 1616.273 us; speedup vs baseline: 1.0128x; 1.0128x over previous
//
#include <hip/hip_runtime.h>

#define N_NODES 50000
#define N_EDGES 400000

typedef __bf16 bf16x8 __attribute__((ext_vector_type(8)));
typedef float f32x4 __attribute__((ext_vector_type(4)));

__device__ __forceinline__ float bflo(uint u){ union{uint i; float f;} v; v.i = u<<16; return v.f; }
__device__ __forceinline__ float bfhi(uint u){ union{uint i; float f;} v; v.i = u & 0xffff0000u; return v.f; }
__device__ __forceinline__ float bf2f(ushort u){ union{uint i; float f;} v; v.i = ((uint)u)<<16; return v.f; }
__device__ __forceinline__ ushort f2bf(float f){
  union{float f; uint i;} v; v.f = f;
  uint r = (v.i + 0x7fffu + ((v.i>>16)&1u))>>16;
  return (ushort)r;
}
__device__ __forceinline__ uint pack2(float a, float b){
  return (uint)f2bf(a) | ((uint)f2bf(b)<<16);
}

// ---------------- f32 -> bf16 convert ------------------------------------------
__global__ __launch_bounds__(256) void f32_to_bf16(
    const float* __restrict__ in, ushort* __restrict__ out, int n)
{
  int i = blockIdx.x*256 + threadIdx.x;
  if (i < n) out[i] = f2bf(in[i]);
}

// f32 -> bf16 with K padding (rows x Kin -> rows x Kout, zeros in pad)
__global__ __launch_bounds__(256) void convert_pad(
    const float* __restrict__ in, ushort* __restrict__ out,
    int rows, int Kin, int Kout)
{
  int i = blockIdx.x*256 + threadIdx.x;
  if (i >= rows*Kout) return;
  int r = i / Kout, c = i - r*Kout;
  out[i] = (c < Kin) ? f2bf(in[(size_t)r*Kin + c]) : (ushort)0;
}

// ---------------- LayerNorm: one wave per node, 2 channels/lane ----------------
__global__ __launch_bounds__(256) void ln_kernel(
    const float* __restrict__ x, const float* __restrict__ w,
    const float* __restrict__ b, ushort* __restrict__ xn)
{
  int n = blockIdx.x*4 + (threadIdx.x>>6);
  if (n >= N_NODES) return;
  int lane = threadIdx.x & 63;
  float2 xp = ((const float2*)x)[(size_t)n*64 + lane];
  float x0 = xp.x, x1 = xp.y;
  float s = x0 + x1, s2 = x0*x0 + x1*x1;
  #pragma unroll
  for (int off=1; off<64; off<<=1){ s += __shfl_xor(s,off); s2 += __shfl_xor(s2,off); }
  float mu  = s*(1.0f/128.0f);
  float var = s2*(1.0f/128.0f) - mu*mu;
  float inv = 1.0f/sqrtf(var + 1e-5f);
  float2 wp = ((const float2*)w)[lane];
  float2 bp = ((const float2*)b)[lane];
  float y0 = (x0-mu)*inv*wp.x + bp.x;
  float y1 = (x1-mu)*inv*wp.y + bp.y;
  ((uint*)xn)[(size_t)n*64 + lane] = pack2(y0, y1);
}

// ---------------- Counting sort by dst -----------------------------------------
__global__ __launch_bounds__(256) void hist_kernel(
    const int* __restrict__ ei, int* __restrict__ cnt)
{
  int e = blockIdx.x*256 + threadIdx.x;
  if (e < N_EDGES) atomicAdd(&cnt[ei[N_EDGES + e]], 1);
}

// single-block exclusive scan of cnt[N_NODES] -> offs[N_NODES+1], cursor copy
__global__ __launch_bounds__(1024) void scan_kernel(
    const int* __restrict__ cnt, int* __restrict__ offs, int* __restrict__ cursor)
{
  __shared__ int wsum[16];
  __shared__ int carry_s;
  int tid = threadIdx.x, lane = tid & 63, wid = tid >> 6;
  if (tid == 0) carry_s = 0;
  __syncthreads();
  for (int base = 0; base < N_NODES; base += 1024){
    int i = base + tid;
    int v = (i < N_NODES) ? cnt[i] : 0;
    int x = v;
    #pragma unroll
    for (int o=1;o<64;o<<=1){ int t=__shfl_up(x,o); if (lane>=o) x+=t; }
    if (lane == 63) wsum[wid] = x;
    __syncthreads();
    if (wid == 0){
      int ws = (lane < 16) ? wsum[lane] : 0;
      #pragma unroll
      for (int o=1;o<16;o<<=1){ int t=__shfl_up(ws,o); if (lane>=o) ws+=t; }
      if (lane < 16) wsum[lane] = ws;
    }
    __syncthreads();
    int wpre = (wid > 0) ? wsum[wid-1] : 0;
    int exc = x + wpre - v;
    int total = wsum[15];
    int o_ = carry_s + exc;
    if (i < N_NODES){ offs[i] = o_; cursor[i] = o_; }
    __syncthreads();
    if (tid == 0) carry_s += total;
    __syncthreads();
  }
  if (tid == 0) offs[N_NODES] = carry_s;
}

// scatter: perm (sorted->orig edge), srcs, dsts, ed = (r, d0, d1, d2)
__global__ __launch_bounds__(256) void scatter_kernel(
    const int* __restrict__ ei, const float* __restrict__ rij,
    const float* __restrict__ dij, int* __restrict__ cursor,
    int* __restrict__ perm, int* __restrict__ srcs, int* __restrict__ dsts,
    float4* __restrict__ ed)
{
  int e = blockIdx.x*256 + threadIdx.x;
  if (e >= N_EDGES) return;
  int d = ei[N_EDGES + e];
  int pos = atomicAdd(&cursor[d], 1);
  perm[pos] = e;
  srcs[pos] = ei[e];
  dsts[pos] = d;
  ed[pos] = make_float4(rij[e], dij[3*(size_t)e], dij[3*(size_t)e+1], dij[3*(size_t)e+2]);
}

// gather fij rows (sorted order) -> bf16, K padded 100 -> 128
__global__ __launch_bounds__(256) void gather_fij(
    int st, int len, const int* __restrict__ perm,
    const float* __restrict__ fij, ushort* __restrict__ out)
{
  int p = blockIdx.x*4 + (threadIdx.x>>6);
  if (p >= len) return;
  int lane = threadIdx.x & 63;
  int eo = perm[st + p];
  uint val = 0;
  if (lane < 50){
    float2 f = *(const float2*)(fij + (size_t)eo*100 + 2*lane);
    val = pack2(f.x, f.y);
  }
  ((uint*)out)[(size_t)p*64 + lane] = val;
}

// ---------------- Generic MFMA GEMM: act(A[M,K] @ W[Nc,K]^T + bias) ------------
// 128x128 tile, BK=32, 4 waves, each wave 64x64 (4x4 frags of 16x16x32 bf16).
// AF32: A operand is f32 in global, converted to bf16 during LDS staging.
// SWZ: 1-D launch of nbx*nby blocks; bijective XCD remap so each XCD owns a
//      contiguous row-chunk range with col fastest (A-tile L2 reuse).
// Epilogue MODEs:
//  0: bf16 store          1: silu -> bf16 store
//  4: aux2f[row*Nc+c] *= vv
//  5: Cf[row*Nc+c] = aux1f[row*Nc+c] + vv    (dx = vdot + o3)
//  6: Cf[row*Nc+c] = vv*bf16(aux1)[(row/3)*Nc+c] + aux2f[row*Nc+c]  (dvec)
//  7: dual-B: atomicAdd(aux2f[(row/3)*Nc+c], (acc1+b1)*(acc2+b2))   (vec_dot)
#define LDP 40  // padded LDS row (bf16 elems)

template<int MODE, int AF32, int SWZ>
__global__ __launch_bounds__(256) void gemm_bt(
    const void* __restrict__ Av, const ushort* __restrict__ W,
    const ushort* __restrict__ W2,
    const float* __restrict__ bias, const float* __restrict__ bias2,
    void* Cptr, const void* aux1, void* aux2,
    int M, int K, int Nc)
{
  __shared__ ushort As[128*LDP];
  __shared__ ushort Bs[128*LDP];
  __shared__ ushort Bs2[(MODE==7) ? 128*LDP : 2];
  const int tid = threadIdx.x;
  int bx, by;
  if (SWZ){
    int nby = Nc >> 7;
    int nwg = gridDim.x;
    int id  = blockIdx.x;
    int q = nwg >> 3, r = nwg & 7;
    int xcd = id & 7, iq = id >> 3;
    int base = (xcd < r) ? xcd*(q+1) : r*(q+1) + (xcd - r)*q;
    int L = base + iq;
    bx = L / nby; by = L - bx*nby;
  } else { bx = blockIdx.x; by = blockIdx.y; }
  const int row0 = bx*128, col0 = by*128;
  const int wave = tid>>6, lane = tid&63;
  const int wm = (wave>>1)*64, wn = (wave&1)*64;
  const int lr = lane&15, lq = lane>>4;
  f32x4 acc[4][4] = {};
  f32x4 acc2[4][4] = {};   // only used when MODE==7

  for (int k0=0; k0<K; k0+=32){
    #pragma unroll
    for (int rnd=0; rnd<2; rnd++){
      int e4 = (rnd*256 + tid)*8;
      int r = e4>>5, c = e4&31;
      int gk = k0 + c;
      { // A tile
        int gr = row0 + r;
        if (AF32){
          const float* Af = (const float*)Av;
          uint2 lo, hi;
          if (gr < M && gk + 8 <= K){
            const float* p = Af + (size_t)gr*K + gk;
            float4 f0 = *(const float4*)p;
            float4 f1 = *(const float4*)(p+4);
            lo = make_uint2(pack2(f0.x,f0.y), pack2(f0.z,f0.w));
            hi = make_uint2(pack2(f1.x,f1.y), pack2(f1.z,f1.w));
          } else {
            float t[8];
            #pragma unroll
            for (int i=0;i<8;i++) t[i] = (gr<M && gk+i<K) ? Af[(size_t)gr*K + gk + i] : 0.0f;
            lo = make_uint2(pack2(t[0],t[1]), pack2(t[2],t[3]));
            hi = make_uint2(pack2(t[4],t[5]), pack2(t[6],t[7]));
          }
          *(uint2*)&As[r*LDP + c]     = lo;
          *(uint2*)&As[r*LDP + c + 4] = hi;
        } else {
          const ushort* Ab = (const ushort*)Av;
          if (gr < M && gk + 8 <= K){
            uint4 t = *(const uint4*)(Ab + (size_t)gr*K + gk);
            *(uint4*)&As[r*LDP + c] = t;
          } else {
            ushort t[8];
            #pragma unroll
            for (int i=0;i<8;i++) t[i] = (gr<M && gk+i<K) ? Ab[(size_t)gr*K + gk + i] : (ushort)0;
            *(uint2*)&As[r*LDP + c]     = make_uint2(((uint)t[0])|((uint)t[1]<<16), ((uint)t[2])|((uint)t[3]<<16));
            *(uint2*)&As[r*LDP + c + 4] = make_uint2(((uint)t[4])|((uint)t[5]<<16), ((uint)t[6])|((uint)t[7]<<16));
          }
        }
      }
      { // B tile (W rows = output channels), bf16 pre-converted
        int gr = col0 + r;
        if (gr < Nc && gk + 8 <= K){
          uint4 t = *(const uint4*)(W + (size_t)gr*K + gk);
          *(uint4*)&Bs[r*LDP + c] = t;
        } else {
          ushort t[8];
          #pragma unroll
          for (int i=0;i<8;i++) t[i] = (gr<Nc && gk+i<K) ? W[(size_t)gr*K + gk + i] : (ushort)0;
          *(uint2*)&Bs[r*LDP + c]     = make_uint2(((uint)t[0])|((uint)t[1]<<16), ((uint)t[2])|((uint)t[3]<<16));
          *(uint2*)&Bs[r*LDP + c + 4] = make_uint2(((uint)t[4])|((uint)t[5]<<16), ((uint)t[6])|((uint)t[7]<<16));
        }
      }
      if (MODE==7){ // second B tile
        int gr = col0 + r;
        if (gr < Nc && gk + 8 <= K){
          uint4 t = *(const uint4*)(W2 + (size_t)gr*K + gk);
          *(uint4*)&Bs2[r*LDP + c] = t;
        } else {
          ushort t[8];
          #pragma unroll
          for (int i=0;i<8;i++) t[i] = (gr<Nc && gk+i<K) ? W2[(size_t)gr*K + gk + i] : (ushort)0;
          *(uint2*)&Bs2[r*LDP + c]     = make_uint2(((uint)t[0])|((uint)t[1]<<16), ((uint)t[2])|((uint)t[3]<<16));
          *(uint2*)&Bs2[r*LDP + c + 4] = make_uint2(((uint)t[4])|((uint)t[5]<<16), ((uint)t[6])|((uint)t[7]<<16));
        }
      }
    }
    __syncthreads();
    bf16x8 af[4], bfr[4];
    #pragma unroll
    for (int i=0;i<4;i++) af[i]  = *(const bf16x8*)&As[(wm + i*16 + lr)*LDP + lq*8];
    #pragma unroll
    for (int i=0;i<4;i++) bfr[i] = *(const bf16x8*)&Bs[(wn + i*16 + lr)*LDP + lq*8];
    #pragma unroll
    for (int i=0;i<4;i++)
      #pragma unroll
      for (int j=0;j<4;j++)
        acc[i][j] = __builtin_amdgcn_mfma_f32_16x16x32_bf16(af[i], bfr[j], acc[i][j], 0,0,0);
    if (MODE==7){
      bf16x8 bfr2[4];
      #pragma unroll
      for (int i=0;i<4;i++) bfr2[i] = *(const bf16x8*)&Bs2[(wn + i*16 + lr)*LDP + lq*8];
      #pragma unroll
      for (int i=0;i<4;i++)
        #pragma unroll
        for (int j=0;j<4;j++)
          acc2[i][j] = __builtin_amdgcn_mfma_f32_16x16x32_bf16(af[i], bfr2[j], acc2[i][j], 0,0,0);
    }
    __syncthreads();
  }

  const ushort* aux1b = (const ushort*)aux1;
  const float*  aux1f = (const float*)aux1;
  float* aux2f = (float*)aux2;

  #pragma unroll
  for (int i=0;i<4;i++){
    int rowb = row0 + wm + i*16 + lq*4;
    #pragma unroll
    for (int j=0;j<4;j++){
      int c = col0 + wn + j*16 + lr;
      float bv  = bias  ? bias[c]  : 0.0f;
      float bv2 = (MODE==7) ? bias2[c] : 0.0f;
      #pragma unroll
      for (int rg=0; rg<4; rg++){
        int row = rowb + rg;
        if (row < M){
          float vv = acc[i][j][rg] + bv;
          size_t idx = (size_t)row*Nc + c;
          if (MODE==0){
            ((ushort*)Cptr)[idx] = f2bf(vv);
          } else if (MODE==1){
            vv = vv/(1.0f + __expf(-vv));
            ((ushort*)Cptr)[idx] = f2bf(vv);
          } else if (MODE==4){
            aux2f[idx] *= vv;
          } else if (MODE==5){
            float r = aux1f[idx] + vv;
            ((float*)Cptr)[idx] = r;
          } else if (MODE==6){
            float o1 = bf2f(aux1b[(size_t)(row/3)*Nc + c]);
            float r = vv*o1 + aux2f[idx];
            ((float*)Cptr)[idx] = r;
          } else if (MODE==7){
            float vv2 = acc2[i][j][rg] + bv2;
            atomicAdd(aux2f + (size_t)(row/3)*Nc + c, vv*vv2);
          }
        }
      }
    }
  }
}

// ---------------- Aggregation: wave per 16 sorted edge positions ---------------
// Run-flush accumulation: accumulate while dst unchanged, one atomic set per run.
// qk: combined q|k rows (node*256 ch; q = [0,128), k = [128,256))
// dkv: chunk rows of 512 ch (dk = [0,128), dv = [128,512)), sorted edge order
#define AGG_G 16

__global__ __launch_bounds__(256) void agg_kernel(
    int st, int len,
    const int* __restrict__ dsts, const int* __restrict__ srcs,
    const float4* __restrict__ ed,
    const ushort* __restrict__ qk, const ushort* __restrict__ v,
    const ushort* __restrict__ vecb, const ushort* __restrict__ dkv,
    float* __restrict__ x_agg, float* __restrict__ vec_agg)
{
  int w = blockIdx.x*4 + (threadIdx.x>>6);
  int p0 = st + w*AGG_G;
  int pend = st + len;
  if (p0 >= pend) return;
  int p1 = p0 + AGG_G; if (p1 > pend) p1 = pend;
  int lane = threadIdx.x & 63;

  const uint* qk32  = (const uint*)qk;
  const uint* v32   = (const uint*)v;
  const uint* vec32 = (const uint*)vecb;
  const uint* dkv32 = (const uint*)dkv;
  int h  = lane>>3;
  int cb = h*24 + (lane&7);                 // uint idx within 48-ch head block
  int f0 = 2*lane;

  int dcur = -1;
  uint qp = 0;
  float xa0=0.f, xa1=0.f;
  float vA0=0.f, vA1=0.f, vB0=0.f, vB1=0.f, vC0=0.f, vC1=0.f;

  for (int p=p0; p<p1; ++p){
    int d = dsts[p];
    if (d != dcur){
      if (dcur >= 0){
        float* xrow = x_agg + (size_t)dcur*128;
        atomicAdd(xrow+f0,   xa0);
        atomicAdd(xrow+f0+1, xa1);
        float* vrow = vec_agg + (size_t)dcur*384;
        atomicAdd(vrow+f0,       vA0); atomicAdd(vrow+f0+1,     vA1);
        atomicAdd(vrow+128+f0,   vB0); atomicAdd(vrow+128+f0+1, vB1);
        atomicAdd(vrow+256+f0,   vC0); atomicAdd(vrow+256+f0+1, vC1);
      }
      dcur = d;
      qp = qk32[(size_t)d*128 + lane];
      xa0=xa1=vA0=vA1=vB0=vB1=vC0=vC1=0.f;
    }
    int src = srcs[p];
    float4 e = ed[p];
    uint kp = qk32[(size_t)src*128 + 64 + lane];
    const uint* dr = dkv32 + (size_t)(p-st)*256;
    uint dkp = dr[lane];
    float s = bflo(qp)*bflo(kp)*bflo(dkp) + bfhi(qp)*bfhi(kp)*bfhi(dkp);
    s += __shfl_xor(s,1); s += __shfl_xor(s,2); s += __shfl_xor(s,4);  // per-head
    float r = e.x;
    float cut = (r < 6.0f) ? 0.5f*(__cosf(r*0.52359877559829887f) + 1.0f) : 0.0f;
    float attn = (s/(1.0f + __expf(-s))) * cut;

    size_t vr = (size_t)src*192;
    const uint* dv = dr + 64;
    uint vx = v32[vr+cb],    dvx = dv[cb];
    uint v1 = v32[vr+cb+8],  dv1 = dv[cb+8];
    uint v2 = v32[vr+cb+16], dv2 = dv[cb+16];
    xa0 += bflo(vx)*bflo(dvx)*attn;
    xa1 += bfhi(vx)*bfhi(dvx)*attn;
    float v1m0 = bflo(v1)*bflo(dv1), v1m1 = bfhi(v1)*bfhi(dv1);
    float v2m0 = bflo(v2)*bflo(dv2), v2m1 = bfhi(v2)*bfhi(dv2);
    uint va  = vec32[vr + lane];
    uint vbx = vec32[vr + 64 + lane];
    uint vc  = vec32[vr + 128 + lane];
    vA0 += bflo(va)*v1m0  + v2m0*e.y;  vA1 += bfhi(va)*v1m1  + v2m1*e.y;
    vB0 += bflo(vbx)*v1m0 + v2m0*e.z;  vB1 += bfhi(vbx)*v1m1 + v2m1*e.z;
    vC0 += bflo(vc)*v1m0  + v2m0*e.w;  vC1 += bfhi(vc)*v1m1  + v2m1*e.w;
  }
  if (dcur >= 0){
    float* xrow = x_agg + (size_t)dcur*128;
    atomicAdd(xrow+f0,   xa0);
    atomicAdd(xrow+f0+1, xa1);
    float* vrow = vec_agg + (size_t)dcur*384;
    atomicAdd(vrow+f0,       vA0); atomicAdd(vrow+f0+1,     vA1);
    atomicAdd(vrow+128+f0,   vB0); atomicAdd(vrow+128+f0+1, vB1);
    atomicAdd(vrow+256+f0,   vC0); atomicAdd(vrow+256+f0+1, vC1);
  }
}

extern "C" void kernel_launch(void* const* d_in, const int* in_sizes, int n_in,
                              void* d_out, int out_size, void* d_ws, size_t ws_size,
                              hipStream_t stream)
{
  (void)in_sizes; (void)n_in; (void)out_size;
  constexpr int Nn = N_NODES, Ee = N_EDGES;
  const float* x    = (const float*)d_in[0];
  const float* vec  = (const float*)d_in[1];
  const int*   eidx = (const int*)  d_in[2];
  const float* rij  = (const float*)d_in[3];
  const float* fij  = (const float*)d_in[4];
  const float* dij  = (const float*)d_in[5];
  const float* lnw  = (const float*)d_in[6];
  const float* lnb  = (const float*)d_in[7];
  const float* Wq   = (const float*)d_in[8];
  const float* bq   = (const float*)d_in[9];
  const float* Wk   = (const float*)d_in[10];
  const float* bk   = (const float*)d_in[11];
  const float* Wv   = (const float*)d_in[12];
  const float* bv   = (const float*)d_in[13];
  const float* Wvec = (const float*)d_in[14];
  const float* bvec = (const float*)d_in[15];
  const float* Wo   = (const float*)d_in[16];
  const float* bo   = (const float*)d_in[17];
  const float* Wdk  = (const float*)d_in[18];
  const float* bdk  = (const float*)d_in[19];
  const float* Wdv  = (const float*)d_in[20];
  const float* bdv  = (const float*)d_in[21];

  // ---- d_out (f32, 25.6M floats) time-multiplexing ----
  // [0 , 6.4M)  floats: qk combined bf16 (node*256 ch) during edge phase
  //                     -> vdot(f32) -> dx(f32)
  // [6.4M,25.6M) floats: vec_agg accumulator (f32) -> dvec (f32, same addresses)
  float*  outf = (float*)d_out;
  ushort* qkb  = (ushort*)d_out;                    // 25.6 MB
  float*  vdot = outf;                              // Nn*128 f32
  float*  vagg = outf + (size_t)Nn*128;             // 3*Nn*128 f32

  // ---- workspace ----
  char* w = (char*)d_ws;
  size_t off = 0;
  auto alloc = [&](size_t bytes){ size_t o = off; off += (bytes + 255) & ~(size_t)255; return o; };

  ushort* WqkB  = (ushort*)(w + alloc(32768*2));    // Wq rows [0,128), Wk [128,256)
  ushort* WvB   = (ushort*)(w + alloc(49152*2));
  ushort* WvecB = (ushort*)(w + alloc(49152*2));
  ushort* WoB   = (ushort*)(w + alloc(49152*2));
  ushort* WdkvP = (ushort*)(w + alloc(512*128*2));  // Wdk|Wdv rows, K padded to 128
  float*  bqk   = (float*) (w + alloc(256*4));
  float*  bdkv  = (float*) (w + alloc(512*4));
  ushort* vecb  = (ushort*)(w + alloc((size_t)3*Nn*128*2));  // 38.4 MB
  ushort* vb    = (ushort*)(w + alloc((size_t)Nn*384*2));    // 38.4 MB
  float*  xagg  = (float*) (w + alloc((size_t)Nn*128*4));    // 25.6 MB
  ushort* o1b   = (ushort*)(w + alloc((size_t)Nn*128*2));    // 12.8 MB
  int*    cnt   = (int*)   (w + alloc((size_t)Nn*4));
  int*    offs  = (int*)   (w + alloc((size_t)(Nn+1)*4));
  int*    cursor= (int*)   (w + alloc((size_t)Nn*4));
  int*    perm  = (int*)   (w + alloc((size_t)Ee*4));
  int*    srcs  = (int*)   (w + alloc((size_t)Ee*4));
  int*    dsts  = (int*)   (w + alloc((size_t)Ee*4));
  float4* ed    = (float4*)(w + alloc((size_t)Ee*16));

  // scratch: xn (12.8 MB) lives here until v GEMM; then fijb + dkv chunks.
  // per-edge chunk scratch: fijb 128ch bf16 (256 B) + dkv 512ch bf16 (1024 B)
  size_t sc_off = off;
  char*  sc = w + sc_off;
  ushort* xn = (ushort*)sc;
  long long chunkC = (ws_size > sc_off) ? (long long)((ws_size - sc_off) / 1280) : 128;
  if (chunkC > 98304) chunkC = 98304;   // keep dkv chunk + gather set L3-resident
  chunkC &= ~127LL;
  if (chunkC < 128) chunkC = 128;
  ushort* fijb = (ushort*)sc;
  ushort* dkvc = (ushort*)(sc + (size_t)chunkC*256);

  // ---- weight / vec conversion ----
  f32_to_bf16<<<(16384+255)/256, 256, 0, stream>>>(Wq,   WqkB,        16384);
  f32_to_bf16<<<(16384+255)/256, 256, 0, stream>>>(Wk,   WqkB+16384,  16384);
  f32_to_bf16<<<(49152+255)/256, 256, 0, stream>>>(Wv,   WvB,   49152);
  f32_to_bf16<<<(49152+255)/256, 256, 0, stream>>>(Wvec, WvecB, 49152);
  f32_to_bf16<<<(49152+255)/256, 256, 0, stream>>>(Wo,   WoB,   49152);
  convert_pad<<<(128*128+255)/256, 256, 0, stream>>>(Wdk, WdkvP,           128, 100, 128);
  convert_pad<<<(384*128+255)/256, 256, 0, stream>>>(Wdv, WdkvP + 128*128, 384, 100, 128);
  f32_to_bf16<<<(3*Nn*128+255)/256, 256, 0, stream>>>(vec, vecb, 3*Nn*128);
  hipMemcpyAsync(bqk,        bq,  128*4, hipMemcpyDeviceToDevice, stream);
  hipMemcpyAsync(bqk + 128,  bk,  128*4, hipMemcpyDeviceToDevice, stream);
  hipMemcpyAsync(bdkv,       bdk, 128*4, hipMemcpyDeviceToDevice, stream);
  hipMemcpyAsync(bdkv + 128, bdv, 384*4, hipMemcpyDeviceToDevice, stream);

  hipMemsetAsync(xagg, 0, (size_t)Nn*128*4, stream);
  hipMemsetAsync(vagg, 0, (size_t)3*Nn*128*4, stream);
  hipMemsetAsync(cnt,  0, (size_t)Nn*4, stream);

  // ---- counting sort of edges by dst ----
  hist_kernel<<<(Ee+255)/256, 256, 0, stream>>>(eidx, cnt);
  scan_kernel<<<1, 1024, 0, stream>>>(cnt, offs, cursor);
  scatter_kernel<<<(Ee+255)/256, 256, 0, stream>>>(eidx, rij, dij, cursor, perm, srcs, dsts, ed);

  ln_kernel<<<(Nn+3)/4, 256, 0, stream>>>(x, lnw, lnb, xn);

  // fused Q|K GEMM (Nc=256) and V GEMM
  gemm_bt<0,0,0><<<dim3((Nn+127)/128, 2), 256, 0, stream>>>(xn, WqkB, nullptr, bqk, nullptr, qkb, nullptr, nullptr, Nn, 128, 256);
  gemm_bt<0,0,0><<<dim3((Nn+127)/128, 3), 256, 0, stream>>>(xn, WvB,  nullptr, bv,  nullptr, vb,  nullptr, nullptr, Nn, 128, 384);

  // edge phase, chunked to stay L3-resident:
  //   gather fij (sorted, bf16, K=128) -> dkv GEMM (XCD-swizzled) -> agg
  for (int st = 0; st < Ee; st += (int)chunkC){
    int len = Ee - st; if (len > (int)chunkC) len = (int)chunkC;
    gather_fij<<<(len+3)/4, 256, 0, stream>>>(st, len, perm, fij, fijb);
    int nbx = (len+127)/128;
    gemm_bt<1,0,1><<<dim3(nbx*4, 1), 256, 0, stream>>>(fijb, WdkvP, nullptr, bdkv, nullptr, dkvc, nullptr, nullptr, len, 128, 512);
    int waves = (len + AGG_G - 1)/AGG_G;
    agg_kernel<<<(waves+3)/4, 256, 0, stream>>>(st, len, dsts, srcs, ed, qkb, vb, vecb, dkvc, xagg, vagg);
  }

  // qkb dead; reuse dx region as f32 vdot accumulator
  hipMemsetAsync(vdot, 0, (size_t)Nn*128*4, stream);
  gemm_bt<7,0,0><<<dim3((3*Nn+127)/128, 1), 256, 0, stream>>>(vecb, WvecB, WvecB + 128*128, bvec, bvec + 128, nullptr, nullptr, vdot, 3*Nn, 128, 128);

  // o1 = xagg@Wo1^T+b ; vdot *= o2 ; dx = vdot + o3 ; dvec = vec3*o1 + vagg
  gemm_bt<0,1,0><<<dim3((Nn+127)/128, 1), 256, 0, stream>>>(xagg, WoB,            nullptr, bo,       nullptr, o1b,    nullptr, nullptr, Nn, 128, 128);
  gemm_bt<4,1,0><<<dim3((Nn+127)/128, 1), 256, 0, stream>>>(xagg, WoB + 128*128,  nullptr, bo + 128, nullptr, nullptr, nullptr, vdot,   Nn, 128, 128);
  gemm_bt<5,1,0><<<dim3((Nn+127)/128, 1), 256, 0, stream>>>(xagg, WoB + 256*128,  nullptr, bo + 256, nullptr, outf,   vdot,    nullptr, Nn, 128, 128);
  gemm_bt<6,0,0><<<dim3((3*Nn+127)/128, 1), 256, 0, stream>>>(vecb, WvecB + 256*128, nullptr, bvec + 256, nullptr, outf + (size_t)Nn*128, o1b, vagg, 3*Nn, 128, 128);
}